// Round 13
// baseline (43.538 us; speedup 1.0000x reference)
//
#include <hip/hip_runtime.h>

#define BATCH 256
#define RPB 32            // rows per block (4 waves x 8 rows)
#define RPW 8             // rows per wave
#define LSTR 260          // LDS row stride in floats (1040 B: 16B-aligned, bank-spread)

typedef float __attribute__((ext_vector_type(4))) fx4;

// ---------------- prep: tiled transpose f->fT + COO segment-bounds scatter ----
__global__ __launch_bounds__(256) void prep_t(
    const float* __restrict__ f, const int* __restrict__ rows,
    int* __restrict__ rstart, int* __restrict__ rend,
    float* __restrict__ fT, int nnz, int dim_in, int TB, int ctiles)
{
    const int bx = blockIdx.x;
    if (bx < TB) {
        __shared__ float lt[32][33];
        const int c0 = (bx % ctiles) * 32;
        const int z0 = (bx / ctiles) * 32;
        const int ic = threadIdx.x & 31;
        const int i0 = threadIdx.x >> 5;          // 0..7
#pragma unroll
        for (int k = 0; k < 4; ++k) {             // lt[a][b] = f[z0+a][c0+b]
            const int a = i0 + 8 * k;
            const int c = c0 + ic;
            lt[a][ic] = (c < dim_in) ? f[(size_t)(z0 + a) * dim_in + c] : 0.0f;
        }
        __syncthreads();
#pragma unroll
        for (int k = 0; k < 4; ++k) {             // fT[c0+b][z0+a], lane->z
            const int b = i0 + 8 * k;
            const int c = c0 + b;
            if (c < dim_in)
                fT[(size_t)c * BATCH + z0 + ic] = lt[ic][b];
        }
    } else {
        const int e = (bx - TB) * 256 + threadIdx.x;
        if (e < nnz) {
            const int r = rows[e];
            if (e == 0 || rows[e - 1] != r) rstart[r] = e;
            if (e == nnz - 1 || rows[e + 1] != r) rend[r] = e + 1;
        }
    }
}

// One WAVE per output row; lanes span z (64 lanes x float4 = 256 z).
// Entry loop is wave-uniform (no divergence); fT reads are 1KB coalesced.
// LDS used once as output-transpose buffer; one barrier per block.
__global__ __launch_bounds__(256) void tsq_rowwave(
    const float* __restrict__ fT, const float* __restrict__ vals,
    const int* __restrict__ ci, const int* __restrict__ cj,
    const int* __restrict__ rstart, const int* __restrict__ rend,
    float* __restrict__ out, int dim_out, int nnz)
{
    __shared__ __align__(16) float ot[RPB][LSTR];   // 33280 B -> 4 blocks/CU

    const int lane = threadIdx.x & 63;
    const int wave = threadIdx.x >> 6;
    const int r0   = blockIdx.x * RPB;

    // ---- compute phase: each wave handles 8 consecutive rows
    for (int i = 0; i < RPW; ++i) {
        const int rl = wave * RPW + i;
        const int r  = r0 + rl;
        fx4 acc = {0.f, 0.f, 0.f, 0.f};
        if (r < dim_out) {
            const int ss = rstart[r];          // wave-uniform broadcast loads
            const int ee = rend[r];
            if (ss >= 0 && ee > ss && ee <= nnz) {
                for (int e = ss; e < ee; ++e) {      // uniform trip count
                    const int   a = ci[e];
                    const int   b = cj[e];
                    const float v = vals[e];
                    const fx4 xa = *(const fx4*)(fT + (size_t)a * BATCH + 4 * lane);
                    const fx4 xb = *(const fx4*)(fT + (size_t)b * BATCH + 4 * lane);
                    acc += v * xa * xb;
                }
            }
        }
        *(fx4*)(&ot[rl][4 * lane]) = acc;      // b128, conflict-free
    }
    __syncthreads();

    // ---- store phase: thread = (row rl = tid&31, quad-sel = tid>>5)
    const int rl   = threadIdx.x & 31;
    const int qsel = threadIdx.x >> 5;         // 0..7
    const int r    = r0 + rl;
    if (r < dim_out) {
        const size_t d = dim_out;
#pragma unroll
        for (int k = 0; k < 8; ++k) {
            const int q = qsel + 8 * k;        // quad index 0..63
            const fx4 v = *(const fx4*)(&ot[rl][4 * q]);
            const int z = 4 * q;
            float* o = out + (size_t)z * d + r;
            __builtin_nontemporal_store(v.x, o);
            __builtin_nontemporal_store(v.y, o + d);
            __builtin_nontemporal_store(v.z, o + 2 * d);
            __builtin_nontemporal_store(v.w, o + 3 * d);
        }
    }
}

// Fallback (workspace too small or BATCH mismatch): reads f directly.
__global__ __launch_bounds__(256) void tsq_fallback(
    const float* __restrict__ f, const float* __restrict__ vals,
    const int* __restrict__ ci, const int* __restrict__ cj,
    const int* __restrict__ rstart, const int* __restrict__ rend,
    float* __restrict__ out, int dim_in, int dim_out, int nnz)
{
    const int r = blockIdx.x * blockDim.x + threadIdx.x;
    if (r >= dim_out) return;
    const int z = blockIdx.y;
    const float* __restrict__ fb = f + (size_t)z * dim_in;
    const int ss = rstart[r];
    const int ee = rend[r];
    float acc = 0.0f;
    if (ss >= 0 && ee > ss && ee <= nnz) {
        for (int e = ss; e < ee; ++e)
            acc += vals[e] * fb[ci[e]] * fb[cj[e]];
    }
    out[(size_t)z * dim_out + r] = acc;
}

extern "C" void kernel_launch(void* const* d_in, const int* in_sizes, int n_in,
                              void* d_out, int out_size, void* d_ws, size_t ws_size,
                              hipStream_t stream)
{
    const float* f    = (const float*)d_in[0];
    const float* vals = (const float*)d_in[1];
    const int*   rows = (const int*)d_in[2];
    const int*   ci   = (const int*)d_in[3];
    const int*   cj   = (const int*)d_in[4];
    float*       out  = (float*)d_out;

    const int nnz     = in_sizes[1];
    const int nF      = in_sizes[0];
    const int dim_in  = nF / BATCH;
    const int dim_out = out_size / BATCH;

    int*   rstart = (int*)d_ws;
    int*   rend   = rstart + dim_out;
    float* fT     = (float*)(rend + dim_out);

    const int use_main = (nF == dim_in * BATCH) &&
                         (ws_size >= (size_t)(2 * dim_out) * 4 + (size_t)nF * 4);

    const int ctiles = (dim_in + 31) / 32;
    const int TB = use_main ? ctiles * (BATCH / 32) : 0;   // transpose tile blocks
    const int NB = (nnz + 255) / 256;                      // bounds blocks
    prep_t<<<TB + NB, 256, 0, stream>>>(f, rows, rstart, rend, fT,
                                        nnz, dim_in, TB, ctiles);

    if (use_main) {
        const int nblk = (dim_out + RPB - 1) / RPB;
        tsq_rowwave<<<nblk, 256, 0, stream>>>(fT, vals, ci, cj, rstart, rend,
                                              out, dim_out, nnz);
    } else {
        dim3 grid((dim_out + 255) / 256, BATCH);
        tsq_fallback<<<grid, 256, 0, stream>>>(f, vals, ci, cj, rstart, rend,
                                               out, dim_in, dim_out, nnz);
    }
}

// Round 14
// 37.239 us; speedup vs baseline: 1.1691x; 1.1691x over previous
//
#include <hip/hip_runtime.h>

#define BATCH 256
#define ZTILE 16          // z per LDS tile
#define NZT 2             // tiles per block -> 32 z; grid.y = 8
#define PADF 20           // floats per fzT stripe (16 z + 4 pad) = 80 B
#define DIN_CAP 416       // dim_in for this problem
#define OSTR 260          // ot row stride (256 r + 4 pad floats)

typedef float __attribute__((ext_vector_type(4))) fx4;

// ---------------- prep: tiled transpose f->fT + COO segment-bounds scatter ----
__global__ __launch_bounds__(256) void prep_t(
    const float* __restrict__ f, const int* __restrict__ rows,
    int* __restrict__ rstart, int* __restrict__ rend,
    float* __restrict__ fT, int nnz, int dim_in, int TB, int ctiles)
{
    const int bx = blockIdx.x;
    if (bx < TB) {
        __shared__ float lt[32][33];
        const int c0 = (bx % ctiles) * 32;
        const int z0 = (bx / ctiles) * 32;
        const int ic = threadIdx.x & 31;
        const int i0 = threadIdx.x >> 5;
#pragma unroll
        for (int k = 0; k < 4; ++k) {
            const int a = i0 + 8 * k;
            const int c = c0 + ic;
            lt[a][ic] = (c < dim_in) ? f[(size_t)(z0 + a) * dim_in + c] : 0.0f;
        }
        __syncthreads();
#pragma unroll
        for (int k = 0; k < 4; ++k) {
            const int b = i0 + 8 * k;
            const int c = c0 + b;
            if (c < dim_in)
                fT[(size_t)c * BATCH + z0 + ic] = lt[ic][b];
        }
    } else {
        const int e = (bx - TB) * 256 + threadIdx.x;
        if (e < nnz) {
            const int r = rows[e];
            if (e == 0 || rows[e - 1] != r) rstart[r] = e;
            if (e == nnz - 1 || rows[e + 1] != r) rend[r] = e + 1;
        }
    }
}

// Barrier that waits only on LDS ops, leaving HBM stores in flight.
__device__ __forceinline__ void lds_sync()
{
    asm volatile("s_waitcnt lgkmcnt(0)" ::: "memory");
    __builtin_amdgcn_sched_barrier(0);
    __builtin_amdgcn_s_barrier();
    __builtin_amdgcn_sched_barrier(0);
}

// R9 compute + LDS output-transpose so each wave store is 1KB contiguous.
__global__ __launch_bounds__(256) void tsq_main(
    const float* __restrict__ fT, const float* __restrict__ vals,
    const int* __restrict__ ci, const int* __restrict__ cj,
    const int* __restrict__ rstart, const int* __restrict__ rend,
    float* __restrict__ out, int dim_in, int dim_out, int nnz)
{
    __shared__ __align__(16) char smem[DIN_CAP * PADF * 4];   // 33280 B; 4 blocks/CU
    float* fzT = (float*)smem;             // compute-phase layout [c][16z] stride PADF
    float* ot  = (float*)smem;             // store-phase layout  [z][256r] stride OSTR

    const int tid = threadIdx.x;
    const int r   = blockIdx.x * 256 + tid;
    const bool valid = (r < dim_out);

    int s = 0, e1 = 0;
    if (valid) {
        const int ss = rstart[r];
        const int ee = rend[r];
        if (ss >= 0 && ee > ss && ee <= nnz) { s = ss; e1 = ee; }   // poison-reject
    }

    const int zbase  = blockIdx.y * (ZTILE * NZT);
    const int nchunk = dim_in * (ZTILE / 4);
    const int lane   = tid & 63;
    const int wv     = tid >> 6;

    for (int t = 0; t < NZT; ++t) {
        const int z0 = zbase + t * ZTILE;

        // ---- stage fzT[c][0..15] = fT[c][z0..z0+15]
        for (int i = tid; i < nchunk; i += 256) {
            const int c  = i >> 2;
            const int zq = i & 3;
            const float4 v = *(const float4*)(fT + (size_t)c * BATCH + z0 + zq * 4);
            *(float4*)(fzT + c * PADF + zq * 4) = v;
        }
        lds_sync();

        // ---- compute: 16 z in 4 float4 accumulators (unchanged from R9)
        float4 a0 = {0,0,0,0}, a1 = {0,0,0,0}, a2 = {0,0,0,0}, a3 = {0,0,0,0};
        for (int e = s; e < e1; ++e) {
            const int   a = ci[e];
            const int   b = cj[e];
            const float v = vals[e];
            const float* ba = fzT + a * PADF;
            const float* bb = fzT + b * PADF;
            float4 xa, xb;
            xa = *(const float4*)(ba);      xb = *(const float4*)(bb);
            a0.x += v*xa.x*xb.x; a0.y += v*xa.y*xb.y; a0.z += v*xa.z*xb.z; a0.w += v*xa.w*xb.w;
            xa = *(const float4*)(ba + 4);  xb = *(const float4*)(bb + 4);
            a1.x += v*xa.x*xb.x; a1.y += v*xa.y*xb.y; a1.z += v*xa.z*xb.z; a1.w += v*xa.w*xb.w;
            xa = *(const float4*)(ba + 8);  xb = *(const float4*)(bb + 8);
            a2.x += v*xa.x*xb.x; a2.y += v*xa.y*xb.y; a2.z += v*xa.z*xb.z; a2.w += v*xa.w*xb.w;
            xa = *(const float4*)(ba + 12); xb = *(const float4*)(bb + 12);
            a3.x += v*xa.x*xb.x; a3.y += v*xa.y*xb.y; a3.z += v*xa.z*xb.z; a3.w += v*xa.w*xb.w;
        }
        lds_sync();   // all gathers done -> fzT storage reusable as ot

        // ---- output transpose: ot[z][tid] = acc[z]  (conflict-free scalar writes)
        ot[ 0*OSTR + tid] = a0.x;  ot[ 1*OSTR + tid] = a0.y;
        ot[ 2*OSTR + tid] = a0.z;  ot[ 3*OSTR + tid] = a0.w;
        ot[ 4*OSTR + tid] = a1.x;  ot[ 5*OSTR + tid] = a1.y;
        ot[ 6*OSTR + tid] = a1.z;  ot[ 7*OSTR + tid] = a1.w;
        ot[ 8*OSTR + tid] = a2.x;  ot[ 9*OSTR + tid] = a2.y;
        ot[10*OSTR + tid] = a2.z;  ot[11*OSTR + tid] = a2.w;
        ot[12*OSTR + tid] = a3.x;  ot[13*OSTR + tid] = a3.y;
        ot[14*OSTR + tid] = a3.z;  ot[15*OSTR + tid] = a3.w;
        lds_sync();

        // ---- stores: wave wv handles z = wv+4k; lane -> 4 consecutive rows.
        // One wave store inst = 64 lanes x 16B = 1KB contiguous in r.
        const int rq = blockIdx.x * 256 + 4 * lane;
#pragma unroll
        for (int k = 0; k < 4; ++k) {
            const int z = wv + 4 * k;
            const fx4 v = *(const fx4*)(ot + z * OSTR + 4 * lane);
            float* o = out + (size_t)(z0 + z) * dim_out + rq;
            if (rq + 3 < dim_out) {
                __builtin_nontemporal_store(v, (fx4*)o);
            } else if (rq < dim_out) {
                const int nrem = dim_out - rq;
                if (nrem > 0) __builtin_nontemporal_store(v.x, o);
                if (nrem > 1) __builtin_nontemporal_store(v.y, o + 1);
                if (nrem > 2) __builtin_nontemporal_store(v.z, o + 2);
            }
        }
        lds_sync();   // ot consumed -> safe to restage fzT next tile
    }
}

// Fallback: reads f directly, one z per block.y.
__global__ __launch_bounds__(256) void tsq_fallback(
    const float* __restrict__ f, const float* __restrict__ vals,
    const int* __restrict__ ci, const int* __restrict__ cj,
    const int* __restrict__ rstart, const int* __restrict__ rend,
    float* __restrict__ out, int dim_in, int dim_out, int nnz)
{
    const int r = blockIdx.x * blockDim.x + threadIdx.x;
    if (r >= dim_out) return;
    const int z = blockIdx.y;
    const float* __restrict__ fb = f + (size_t)z * dim_in;
    const int ss = rstart[r];
    const int ee = rend[r];
    float acc = 0.0f;
    if (ss >= 0 && ee > ss && ee <= nnz) {
        for (int e = ss; e < ee; ++e)
            acc += vals[e] * fb[ci[e]] * fb[cj[e]];
    }
    out[(size_t)z * dim_out + r] = acc;
}

extern "C" void kernel_launch(void* const* d_in, const int* in_sizes, int n_in,
                              void* d_out, int out_size, void* d_ws, size_t ws_size,
                              hipStream_t stream)
{
    const float* f    = (const float*)d_in[0];
    const float* vals = (const float*)d_in[1];
    const int*   rows = (const int*)d_in[2];
    const int*   ci   = (const int*)d_in[3];
    const int*   cj   = (const int*)d_in[4];
    float*       out  = (float*)d_out;

    const int nnz     = in_sizes[1];
    const int nF      = in_sizes[0];
    const int dim_in  = nF / BATCH;
    const int dim_out = out_size / BATCH;

    int*   rstart = (int*)d_ws;
    int*   rend   = rstart + dim_out;
    float* fT     = (float*)(rend + dim_out);

    const int use_main = (dim_in <= DIN_CAP) &&
                         (ws_size >= (size_t)(2 * dim_out) * 4 + (size_t)nF * 4);

    const int ctiles = (dim_in + 31) / 32;
    const int TB = use_main ? ctiles * (BATCH / 32) : 0;
    const int NB = (nnz + 255) / 256;
    prep_t<<<TB + NB, 256, 0, stream>>>(f, rows, rstart, rend, fT,
                                        nnz, dim_in, TB, ctiles);

    if (use_main) {
        dim3 grid((dim_out + 255) / 256, BATCH / (ZTILE * NZT));
        tsq_main<<<grid, 256, 0, stream>>>(fT, vals, ci, cj, rstart, rend, out,
                                           dim_in, dim_out, nnz);
    } else {
        dim3 grid((dim_out + 255) / 256, BATCH);
        tsq_fallback<<<grid, 256, 0, stream>>>(f, vals, ci, cj, rstart, rend,
                                               out, dim_in, dim_out, nnz);
    }
}